// Round 10
// baseline (377.795 us; speedup 1.0000x reference)
//
#include <hip/hip_runtime.h>
#include <math.h>

#define NN 100000
#define NE 1600000
#define F_IN 128
#define HEADS 4
#define HC 128
#define NEG_SLOPE 0.2f
#define NBKT 391    // buckets of 256 dst nodes: (NN+255)/256  (scatter-coalescing optimum)
#define BCAP 5120   // bucket capacity (mean 4096, sd 64 -> +16 sigma; R0-proven)
#define LDK 136     // padded LDS row (bf16): 128 + 8 -> 2-way bank alias (free)
#define NSTRIP 6250 // NN/16

typedef __attribute__((ext_vector_type(8))) short bf16x8;
typedef __attribute__((ext_vector_type(4))) float f32x4;

static __device__ __forceinline__ short f2bf_rne(float f) {
    unsigned u = __float_as_uint(f);
    unsigned r = (u + 0x7FFFu + ((u >> 16) & 1u)) >> 16;
    return (short)r;
}
// 2x f32 -> packed bf16 (RNE), one instruction
static __device__ __forceinline__ unsigned cvt_pk_bf16(float a, float b) {
    unsigned r;
    asm("v_cvt_pk_bf16_f32 %0, %1, %2" : "=v"(r) : "v"(a), "v"(b));
    return r;
}

// ---------------------------------------------------------------------------
// Kernel 1: W prep (transpose + bf16, hi only) + int64/int32 detect (blk 0).
__global__ __launch_bounds__(256) void prep_kernel(
        const float* __restrict__ W, short* __restrict__ wt_hi,
        const int* __restrict__ ei, int* __restrict__ flag) {
    if (blockIdx.x == 0 && threadIdx.x < 64) {
        int l = threadIdx.x;
        int v = ei[2 * l + 1];
        for (int off = 1; off < 64; off <<= 1) v |= __shfl_xor(v, off);
        if (l == 0) *flag = (v == 0) ? 1 : 0;   // 1 => int64 layout
    }
    int i = blockIdx.x * 256 + threadIdx.x;
    if (i >= F_IN * HC) return;
    int k = i >> 7, n = i & 127;
    wt_hi[n * F_IN + k] = f2bf_rne(W[k * HC + n]);
}

// ---------------------------------------------------------------------------
// Kernel 2: bucketed multisplit, 256-node buckets (R8/R9-passing structure).
__global__ __launch_bounds__(256) void bucket_scatter_kernel(
        const int* __restrict__ ei, const int* __restrict__ flag,
        int* __restrict__ bcur, unsigned* __restrict__ pairs) {
    __shared__ int lhist[NBKT];
    __shared__ int gbase[NBKT];
    int t = threadIdx.x;
    for (int i = t; i < NBKT; i += 256) lhist[i] = 0;
    __syncthreads();
    int is64 = *flag;
    int base = blockIdx.x * 4096;

    unsigned wrd[16];
    int meta[16];
    if (is64) {
#pragma unroll
        for (int it = 0; it < 8; ++it) {
            int e = base + it * 512 + 2 * t;      // edges e, e+1 (e even, NE even)
            if (e < NE) {
                int4 sv = *(const int4*)(ei + 2 * (size_t)e);
                int4 dv = *(const int4*)(ei + 2 * (size_t)NE + 2 * (size_t)e);
                int b0 = dv.x >> 8;
                int r0 = atomicAdd(&lhist[b0], 1);
                wrd[2 * it] = (unsigned)sv.x | ((unsigned)(dv.x & 255) << 17);
                meta[2 * it] = b0 | (r0 << 9);
                int b1 = dv.z >> 8;
                int r1 = atomicAdd(&lhist[b1], 1);
                wrd[2 * it + 1] = (unsigned)sv.z | ((unsigned)(dv.z & 255) << 17);
                meta[2 * it + 1] = b1 | (r1 << 9);
            } else {
                meta[2 * it] = -1;
                meta[2 * it + 1] = -1;
            }
        }
    } else {
#pragma unroll
        for (int it = 0; it < 16; ++it) {
            int e = base + it * 256 + t;
            if (e < NE) {
                int src = ei[e];
                int dst = ei[NE + e];
                int b = dst >> 8;
                int r = atomicAdd(&lhist[b], 1);
                wrd[it] = (unsigned)src | ((unsigned)(dst & 255) << 17);
                meta[it] = b | (r << 9);
            } else {
                meta[it] = -1;
            }
        }
    }
    __syncthreads();
    for (int i = t; i < NBKT; i += 256)
        gbase[i] = lhist[i] ? atomicAdd(&bcur[i], lhist[i]) : 0;
    __syncthreads();
#pragma unroll
    for (int it = 0; it < 16; ++it) {
        if (meta[it] >= 0) {
            int b = meta[it] & 511;
            int r = meta[it] >> 9;
            pairs[(size_t)b * BCAP + gbase[b] + r] = wrd[it];
        }
    }
}

// ---------------------------------------------------------------------------
// Kernel 3: h = x @ W, 2-term split-bf16 MFMA (R9-passing core). Output now
// HEAD-MAJOR: hq[head][node][32 bf16] -- 6.4 MB per head slice, so head-sliced
// aggregation blocks touch only their slice (XCD L2 footprint 25.6 -> 6.4 MB).
__global__ __launch_bounds__(512) void mfma_gemm_kernel(
        const float* __restrict__ x, const short* __restrict__ wt_hi,
        unsigned short* __restrict__ hq) {
    __shared__ short lw[128 * LDK];   // 34.8 KB: ALL 128 W rows
    int t = threadIdx.x;

    for (int c = t; c < 2048; c += 512) {
        int n = c >> 4;
        int kk = (c & 15) * 8;
        *(bf16x8*)(lw + n * LDK + kk) = *(const bf16x8*)(wt_hi + n * F_IN + kk);
    }
    __syncthreads();

    int strip = blockIdx.x * 8 + (t >> 6);
    if (strip >= NSTRIP) return;       // no barriers after this point
    int lane = t & 63;
    int l15 = lane & 15;
    int q = lane >> 4;

    f32x4 acc[8];
#pragma unroll
    for (int nt = 0; nt < 8; ++nt) acc[nt] = (f32x4){0.f, 0.f, 0.f, 0.f};

    union BU { bf16x8 v; unsigned u[4]; };
    const float* xp = x + (size_t)(strip * 16 + l15) * F_IN + q * 8;

#pragma unroll
    for (int ki = 0; ki < 4; ++ki) {
        float4 v0 = *(const float4*)(xp + ki * 32);
        float4 v1 = *(const float4*)(xp + ki * 32 + 4);
        float vv[8] = {v0.x, v0.y, v0.z, v0.w, v1.x, v1.y, v1.z, v1.w};
        BU ah, al;
#pragma unroll
        for (int j = 0; j < 4; ++j) {
            float f0 = vv[2 * j], f1 = vv[2 * j + 1];
            unsigned hp = cvt_pk_bf16(f0, f1);
            ah.u[j] = hp;
            float r0 = f0 - __uint_as_float(hp << 16);
            float r1 = f1 - __uint_as_float(hp & 0xFFFF0000u);
            al.u[j] = cvt_pk_bf16(r0, r1);
        }
        int koff = ki * 32 + q * 8;
#pragma unroll
        for (int nt = 0; nt < 8; ++nt) {
            bf16x8 bh = *(const bf16x8*)(lw + (nt * 16 + l15) * LDK + koff);
            acc[nt] = __builtin_amdgcn_mfma_f32_16x16x32_bf16(ah.v, bh, acc[nt], 0, 0, 0);
            acc[nt] = __builtin_amdgcn_mfma_f32_16x16x32_bf16(al.v, bh, acc[nt], 0, 0, 0);
        }
    }

    int orow = strip * 16 + q * 4;
#pragma unroll
    for (int nt = 0; nt < 8; ++nt) {
        int hd = nt >> 1;
        int colh = (nt & 1) * 16 + l15;
#pragma unroll
        for (int r = 0; r < 4; ++r)
            hq[(size_t)hd * NN * 32 + (size_t)(orow + r) * 32 + colh] =
                (unsigned short)f2bf_rne(acc[nt][r]);
    }
}

// ---------------------------------------------------------------------------
// Kernel 4: attention dots from head-major bf16 h. One wave per node row.
__global__ __launch_bounds__(256) void attdot_kernel(
        const unsigned* __restrict__ hq_u, const float* __restrict__ att_src,
        const float* __restrict__ att_dst,
        float* __restrict__ a_src, float* __restrict__ a_dst) {
    int row = (blockIdx.x * 256 + threadIdx.x) >> 6;
    if (row >= NN) return;
    int lane = threadIdx.x & 63;
    int hd = lane >> 4;
    int l15 = lane & 15;
    unsigned u = hq_u[(size_t)hd * NN * 16 + (size_t)row * 16 + l15];
    float f0 = __uint_as_float(u << 16);
    float f1 = __uint_as_float(u & 0xFFFF0000u);
    float as0 = att_src[hd * 32 + 2 * l15];
    float as1 = att_src[hd * 32 + 2 * l15 + 1];
    float ad0 = att_dst[hd * 32 + 2 * l15];
    float ad1 = att_dst[hd * 32 + 2 * l15 + 1];
    float ps = f0 * as0 + f1 * as1;
    float pd = f0 * ad0 + f1 * ad1;
#pragma unroll
    for (int off = 1; off < 16; off <<= 1) {
        ps += __shfl_xor(ps, off);
        pd += __shfl_xor(pd, off);
    }
    if (l15 == 0) {
        a_src[row * 4 + hd] = ps;
        a_dst[row * 4 + hd] = pd;
    }
}

// ---------------------------------------------------------------------------
// Kernel 5: bucket -> CSR + per-edge bf16 weights (R8/R9-passing structure).
// Weights now stored HEAD-MAJOR: walh[head][edge] (2B each), so a head-sliced
// aggr pass reads only 2 B/edge.
__global__ __launch_bounds__(1024) void bucket_csr_kernel(
        const int* __restrict__ bcur, const unsigned* __restrict__ pairs,
        const float* __restrict__ a_src, const float* __restrict__ a_dst,
        int* __restrict__ deg, int* __restrict__ offsets,
        int* __restrict__ csr_src, unsigned short* __restrict__ walh) {
    __shared__ unsigned lpairs[BCAP];   // 20 KB
    __shared__ int sd[1024];            // 4 KB
    __shared__ int cnt256[256];
    __shared__ int lcur[256];

    int b = blockIdx.x;
    int t = threadIdx.x;

    // bucket base = prefix sum of bcur[0..b)
    int partial = 0;
    for (int i = t; i < b; i += 1024) partial += bcur[i];
    sd[t] = partial;
    __syncthreads();
    for (int off = 512; off > 0; off >>= 1) {
        if (t < off) sd[t] += sd[t + off];
        __syncthreads();
    }
    int bktbase = sd[0];
    __syncthreads();

    if (t < 256) cnt256[t] = 0;
    __syncthreads();

    int cnt = bcur[b];
    const unsigned* __restrict__ bp = pairs + (size_t)b * BCAP;
    for (int i = t; i < cnt; i += 1024) {
        unsigned w = bp[i];
        lpairs[i] = w;
        atomicAdd(&cnt256[w >> 17], 1);
    }
    __syncthreads();

    // exclusive scan over the 256 per-node counts (first 256 threads; guarded)
    if (t < 256) sd[t] = cnt256[t];
    __syncthreads();
    for (int off = 1; off < 256; off <<= 1) {
        int u = 0;
        if (t < 256 && t >= off) u = sd[t - off];
        __syncthreads();
        if (t < 256) sd[t] += u;
        __syncthreads();
    }
    if (t < 256) {
        int v = cnt256[t];
        int myoff = bktbase + sd[t] - v;
        int node = (b << 8) + t;
        if (node < NN) {
            deg[node] = v;
            offsets[node] = myoff;
        }
        lcur[t] = myoff;
    }
    __syncthreads();

#define CSR_EMIT(w_, as_, ad_)                                                  \
    {                                                                           \
        int src_ = (int)(w_ & 0x1FFFFu);                                        \
        int dl_ = (int)(w_ >> 17);                                              \
        float e0 = as_.x + ad_.x; e0 = (e0 < 0.f) ? NEG_SLOPE * e0 : e0;        \
        float e1 = as_.y + ad_.y; e1 = (e1 < 0.f) ? NEG_SLOPE * e1 : e1;        \
        float e2 = as_.z + ad_.z; e2 = (e2 < 0.f) ? NEG_SLOPE * e2 : e2;        \
        float e3 = as_.w + ad_.w; e3 = (e3 < 0.f) ? NEG_SLOPE * e3 : e3;        \
        float w0 = __expf(e0), w1 = __expf(e1), w2 = __expf(e2), w3 = __expf(e3); \
        int pos = atomicAdd(&lcur[dl_], 1);                                     \
        csr_src[pos] = src_;                                                    \
        walh[pos]                      = (unsigned short)f2bf_rne(w0);          \
        walh[(size_t)NE + pos]         = (unsigned short)f2bf_rne(w1);          \
        walh[(size_t)2 * NE + pos]     = (unsigned short)f2bf_rne(w2);          \
        walh[(size_t)3 * NE + pos]     = (unsigned short)f2bf_rne(w3);          \
    }

    {
        int i1 = t + 1024, i2 = t + 2048, i3 = t + 3072;
        int v0 = (t < cnt), v1 = (i1 < cnt), v2 = (i2 < cnt), v3 = (i3 < cnt);
        unsigned w0 = 0, w1 = 0, w2 = 0, w3 = 0;
        if (v0) w0 = lpairs[t];
        if (v1) w1 = lpairs[i1];
        if (v2) w2 = lpairs[i2];
        if (v3) w3 = lpairs[i3];
        float4 as0, ad0, as1, ad1, as2, ad2, as3, ad3;
        if (v0) { as0 = ((const float4*)a_src)[w0 & 0x1FFFFu]; ad0 = ((const float4*)a_dst)[(b << 8) + (w0 >> 17)]; }
        if (v1) { as1 = ((const float4*)a_src)[w1 & 0x1FFFFu]; ad1 = ((const float4*)a_dst)[(b << 8) + (w1 >> 17)]; }
        if (v2) { as2 = ((const float4*)a_src)[w2 & 0x1FFFFu]; ad2 = ((const float4*)a_dst)[(b << 8) + (w2 >> 17)]; }
        if (v3) { as3 = ((const float4*)a_src)[w3 & 0x1FFFFu]; ad3 = ((const float4*)a_dst)[(b << 8) + (w3 >> 17)]; }
        if (v0) CSR_EMIT(w0, as0, ad0);
        if (v1) CSR_EMIT(w1, as1, ad1);
        if (v2) CSR_EMIT(w2, as2, ad2);
        if (v3) CSR_EMIT(w3, as3, ad3);
        for (int i = t + 4096; i < cnt; i += 1024) {
            unsigned w = lpairs[i];
            float4 as = ((const float4*)a_src)[w & 0x1FFFFu];
            float4 ad = ((const float4*)a_dst)[(b << 8) + (w >> 17)];
            CSR_EMIT(w, as, ad);
        }
    }
#undef CSR_EMIT
}

// ---------------------------------------------------------------------------
// Kernel 6: HEAD-SLICED per-node aggregation. Block b: head q = b&3 (under
// round-robin block->XCD dispatch, head-q blocks land on XCDs {q, q+4} ->
// each XCD's L2 only ever touches its 6.4 MB h-slice). Wave = one (dst, head);
// 4 subgroups of 16 lanes process 4 consecutive edges (no divergence, one
// fully-consumed 64B line per gather); cross-subgroup shfl reduce at the end.
__global__ __launch_bounds__(256) void gat_aggr_kernel(
        const int* __restrict__ offsets, const int* __restrict__ deg,
        const int* __restrict__ csr_src, const unsigned short* __restrict__ walh,
        const float* __restrict__ a_src, const float* __restrict__ a_dst,
        const unsigned* __restrict__ hq_u, const float* __restrict__ bias,
        float* __restrict__ out) {
    int b = blockIdx.x;
    int q = b & 3;                         // head (XCD-affine)
    int dst = (b >> 2) * 4 + (threadIdx.x >> 6);
    int lane = threadIdx.x & 63;
    int sub = lane >> 4;
    int l15 = lane & 15;

    int start = offsets[dst];
    int n = deg[dst];
    const unsigned* __restrict__ hqq = hq_u + (size_t)q * NN * 16;
    const unsigned short* __restrict__ wq = walh + (size_t)q * NE;

    float accx = 0.f, accy = 0.f, wsum = 0.f;
    int j = 0;
    for (; j + 7 < n; j += 8) {            // 2 edges per subgroup in flight
        int e0 = start + j + sub;
        int e1 = e0 + 4;
        int s0 = csr_src[e0];
        int s1 = csr_src[e1];
        float w0 = __uint_as_float((unsigned)wq[e0] << 16);
        float w1 = __uint_as_float((unsigned)wq[e1] << 16);
        unsigned u0 = hqq[(size_t)s0 * 16 + l15];
        unsigned u1 = hqq[(size_t)s1 * 16 + l15];
        wsum += w0 + w1;
        accx += w0 * __uint_as_float(u0 << 16);
        accy += w0 * __uint_as_float(u0 & 0xFFFF0000u);
        accx += w1 * __uint_as_float(u1 << 16);
        accy += w1 * __uint_as_float(u1 & 0xFFFF0000u);
    }
    for (; j < n; j += 4) {                // predicated tail
        int idx = j + sub;
        if (idx < n) {
            int e0 = start + idx;
            int s0 = csr_src[e0];
            float w0 = __uint_as_float((unsigned)wq[e0] << 16);
            unsigned u0 = hqq[(size_t)s0 * 16 + l15];
            wsum += w0;
            accx += w0 * __uint_as_float(u0 << 16);
            accy += w0 * __uint_as_float(u0 & 0xFFFF0000u);
        }
    }
    // reduce across the 4 subgroups (lane bits 4 and 5)
    accx += __shfl_xor(accx, 16); accx += __shfl_xor(accx, 32);
    accy += __shfl_xor(accy, 16); accy += __shfl_xor(accy, 32);
    wsum += __shfl_xor(wsum, 16); wsum += __shfl_xor(wsum, 32);

    if (sub == 0) {
        float e = a_src[dst * 4 + q] + a_dst[dst * 4 + q];
        e = (e < 0.f) ? NEG_SLOPE * e : e;
        float sf = __expf(e);
        float inv = 1.f / (wsum + sf + 1e-16f);
        unsigned us = hqq[(size_t)dst * 16 + l15];
        float2 b2 = ((const float2*)bias)[q * 16 + l15];
        float ox = tanhf((accx + sf * __uint_as_float(us << 16)) * inv + b2.x);
        float oy = tanhf((accy + sf * __uint_as_float(us & 0xFFFF0000u)) * inv + b2.y);
        ((float2*)out)[(size_t)dst * 64 + q * 16 + l15] = make_float2(ox, oy);
    }
}

// ---------------------------------------------------------------------------
extern "C" void kernel_launch(void* const* d_in, const int* in_sizes, int n_in,
                              void* d_out, int out_size, void* d_ws, size_t ws_size,
                              hipStream_t stream) {
    const float* x       = (const float*)d_in[0];
    const int*   ei      = (const int*)  d_in[1];
    const float* W       = (const float*)d_in[2];
    const float* att_src = (const float*)d_in[3];
    const float* att_dst = (const float*)d_in[4];
    const float* bias    = (const float*)d_in[5];
    float* out = (float*)d_out;

    unsigned short* hq = (unsigned short*)d_ws;              // 4 x NN x 32 bf16 (25.6 MB, head-major)
    float* a_src = (float*)(hq + (size_t)NN * HC);           // NN*4
    float* a_dst = a_src + (size_t)NN * HEADS;               // NN*4
    short* wt_hi = (short*)(a_dst + (size_t)NN * HEADS);     // 16384
    int* flag    = (int*)(wt_hi + F_IN * HC);
    int* bcur    = flag + 4;                 // NBKT
    int* deg     = bcur + NBKT + 1;          // NN
    int* offsets = deg + NN;                 // NN
    int* csr_src = offsets + NN;             // NE (6.4 MB)
    unsigned short* walh = (unsigned short*)(csr_src + NE);  // 4 x NE bf16 (12.8 MB, head-major)
    unsigned* pairs = (unsigned*)(walh + (size_t)4 * NE);    // NBKT*BCAP (8 MB)

    hipMemsetAsync(bcur, 0, NBKT * sizeof(int), stream);

    hipLaunchKernelGGL(prep_kernel, dim3(64), dim3(256), 0, stream,
                       W, wt_hi, ei, flag);

    hipLaunchKernelGGL(bucket_scatter_kernel, dim3((NE + 4095) / 4096), dim3(256), 0, stream,
                       ei, flag, bcur, pairs);

    hipLaunchKernelGGL(mfma_gemm_kernel, dim3(782), dim3(512), 0, stream,
                       x, wt_hi, hq);

    hipLaunchKernelGGL(attdot_kernel, dim3(NN * 64 / 256), dim3(256), 0, stream,
                       (const unsigned*)hq, att_src, att_dst, a_src, a_dst);

    hipLaunchKernelGGL(bucket_csr_kernel, dim3(NBKT), dim3(1024), 0, stream,
                       bcur, pairs, a_src, a_dst, deg, offsets, csr_src, walh);

    // head-sliced aggregation: block = 4 waves = 4 dsts of one head
    hipLaunchKernelGGL(gat_aggr_kernel, dim3(NN), dim3(256), 0, stream,
                       offsets, deg, csr_src, walh, a_src, a_dst,
                       (const unsigned*)hq, bias, out);
}